// Round 1
// baseline (503.192 us; speedup 1.0000x reference)
//
#include <hip/hip_runtime.h>
#include <stdint.h>

typedef __bf16 bf16;
typedef __bf16 bf16x4 __attribute__((ext_vector_type(4)));
typedef __bf16 bf16x8 __attribute__((ext_vector_type(8)));
typedef float  f32x4  __attribute__((ext_vector_type(4)));

#define MFMA16(A, B, C) __builtin_amdgcn_mfma_f32_16x16x32_bf16((A), (B), (C), 0, 0, 0)

// Problem constants
// B=960 windows, N=144 patches, DIM=192, HEADS=6, hd=32, TYPES=64, n_mask=15
// ws layout (bytes):
//   wqkvt [576][192] bf16 @ 0          (221184)
//   woutt [192][192] bf16 @ 221184     (73728)
//   qb    [960][6][144][32] bf16 @ 294912      (53084160)
//   kb    same                @ 53379072
//   vtb   [960][6][32][144]   @ 106463232
//   obuf  [960][144][192]     @ 159547392      (total 212631552 B)

// ---------------- weight transpose + bf16 cast ----------------
__global__ __launch_bounds__(256) void k_prep(const float* __restrict__ wqkv,
                                              const float* __restrict__ wout,
                                              bf16* __restrict__ wqkvt,
                                              bf16* __restrict__ woutt) {
    int i = blockIdx.x * 256 + threadIdx.x;   // grid = 576 blocks -> i < 147456 exactly
    if (i < 576 * 192) {
        int n = i / 192, k = i - n * 192;
        wqkvt[i] = (bf16)wqkv[k * 576 + n];   // [n][k], k-contiguous
    } else {
        int j = i - 576 * 192;
        int n = j / 192, k = j - n * 192;
        woutt[j] = (bf16)wout[k * 192 + n];
    }
}

// ---------------- QKV projection GEMM ----------------
// grid 2160 (64 rows each), 512 threads = 8 waves: wave = (rt = wid&3 row-tile, ch = wid>>2 col-half)
__global__ __launch_bounds__(512) void k_qkv(const float* __restrict__ x,
                                             const float* __restrict__ bqkv,
                                             const bf16* __restrict__ wt,
                                             bf16* __restrict__ qb,
                                             bf16* __restrict__ kb,
                                             bf16* __restrict__ vtb) {
    __shared__ bf16 wch[576][40];   // k-step W chunk, padded 32->40 (2-way max bank conflict)
    const int tid = threadIdx.x;
    const int lane = tid & 63;
    const int wid = tid >> 6;
    const int rt = wid & 3;
    const int ch = wid >> 2;
    const int l15 = lane & 15;
    const int g = lane >> 4;
    const int m0 = blockIdx.x * 64;

    f32x4 acc[18];
    for (int i = 0; i < 18; ++i) acc[i] = (f32x4){0.f, 0.f, 0.f, 0.f};

    const float* xp = x + (size_t)(m0 + rt * 16 + l15) * 192 + g * 8;

    for (int ks = 0; ks < 6; ++ks) {
        __syncthreads();
        for (int i = tid; i < 2304; i += 512) {          // stage 576 rows x 32 k (36 KB)
            int row = i >> 2, c = i & 3;
            bf16x8 v = *reinterpret_cast<const bf16x8*>(wt + row * 192 + ks * 32 + c * 8);
            *reinterpret_cast<bf16x8*>(&wch[row][c * 8]) = v;
        }
        __syncthreads();
        f32x4 xa = *reinterpret_cast<const f32x4*>(xp + ks * 32);
        f32x4 xb = *reinterpret_cast<const f32x4*>(xp + ks * 32 + 4);
        bf16x8 a;
        a[0] = (bf16)xa[0]; a[1] = (bf16)xa[1]; a[2] = (bf16)xa[2]; a[3] = (bf16)xa[3];
        a[4] = (bf16)xb[0]; a[5] = (bf16)xb[1]; a[6] = (bf16)xb[2]; a[7] = (bf16)xb[3];
        #pragma unroll
        for (int ct = 0; ct < 18; ++ct) {
            int col = ch * 288 + ct * 16 + l15;
            bf16x8 b = *reinterpret_cast<const bf16x8*>(&wch[col][g * 8]);
            acc[ct] = MFMA16(a, b, acc[ct]);
        }
    }

    // epilogue: scatter to q/k ([b][h][n][32]) and v transposed ([b][h][32][n])
    const int rowb = m0 + rt * 16 + g * 4;     // 4-row group, never crosses a 144 boundary
    const int bidx = rowb / 144;
    const int n0 = rowb - bidx * 144;
    #pragma unroll
    for (int ct = 0; ct < 18; ++ct) {
        int c = ch * 288 + ct * 16 + l15;      // global col in [0,576)
        float bias = bqkv[c];
        int qi = c / 192;
        int rem = c - qi * 192;
        int h = rem >> 5;
        int d = rem & 31;
        if (qi == 2) {
            bf16x4 v;
            v[0] = (bf16)(acc[ct][0] + bias);
            v[1] = (bf16)(acc[ct][1] + bias);
            v[2] = (bf16)(acc[ct][2] + bias);
            v[3] = (bf16)(acc[ct][3] + bias);
            *reinterpret_cast<bf16x4*>(vtb + ((size_t)(bidx * 6 + h) * 32 + d) * 144 + n0) = v;
        } else {
            bf16* dst = (qi == 0 ? qb : kb) + ((size_t)(bidx * 6 + h) * 144 + n0) * 32 + d;
            dst[0]  = (bf16)(acc[ct][0] + bias);
            dst[32] = (bf16)(acc[ct][1] + bias);
            dst[64] = (bf16)(acc[ct][2] + bias);
            dst[96] = (bf16)(acc[ct][3] + bias);
        }
    }
}

// ---------------- windowed attention ----------------
// grid 5760 = (b,h); 576 threads = 9 waves; wave wv owns S rows [16wv,16wv+16)
__global__ __launch_bounds__(576) void k_attn(const bf16* __restrict__ qb,
                                              const bf16* __restrict__ kb,
                                              const bf16* __restrict__ vtb,
                                              const float* __restrict__ mask,
                                              const float* __restrict__ btab,
                                              bf16* __restrict__ ob) {
    __shared__ bf16 pl[144][168];   // P rows; m padded 144->160 zeros; stride 168 for banks
    const int bid = blockIdx.x;
    const int b = bid / 6;
    const int h = bid - b * 6;
    const int t = b & 63;           // bias type  = b % 64
    const int wm = b % 15;          // mask index = b % 15
    const int tid = threadIdx.x;
    const int lane = tid & 63;
    const int wv = tid >> 6;
    const int l15 = lane & 15;
    const int g = lane >> 4;

    const bf16* qp = qb + (size_t)bid * 4608;
    const bf16* kp = kb + (size_t)bid * 4608;
    const bf16* vp = vtb + (size_t)bid * 4608;

    // zero the m-pad columns [144,160) of this wave's own rows (no barrier needed)
    if (lane < 32) {
        bf16x8 z;
        #pragma unroll
        for (int i = 0; i < 8; ++i) z[i] = (bf16)0.f;
        *reinterpret_cast<bf16x8*>(&pl[wv * 16 + (lane >> 1)][144 + (lane & 1) * 8]) = z;
    }

    // ---- QK^T (hd=32 -> single K-step per 16x16 tile) ----
    bf16x8 aq = *reinterpret_cast<const bf16x8*>(qp + (wv * 16 + l15) * 32 + g * 8);
    f32x4 s[9];
    #pragma unroll
    for (int ct = 0; ct < 9; ++ct) {
        bf16x8 bk = *reinterpret_cast<const bf16x8*>(kp + (ct * 16 + l15) * 32 + g * 8);
        f32x4 z = (f32x4){0.f, 0.f, 0.f, 0.f};
        s[ct] = MFMA16(aq, bk, z);
    }

    // ---- scale + earth bias + mask, fp32 softmax ----
    const float scale = 0.17677669529663687f;  // 1/sqrt(32)
    int npart[4], nrow[4];
    #pragma unroll
    for (int r = 0; r < 4; ++r) {
        int n = wv * 16 + g * 4 + r;           // C/D row = (lane>>4)*4 + reg  [verified layout]
        nrow[r] = n;
        int zn = n / 72, rmn = n - zn * 72;
        int hn = rmn / 12, wn = rmn - hn * 12;
        npart[r] = 828 * zn + 23 * hn + wn + 11;
    }
    const float* mrow = mask + (size_t)wm * 20736;
    const float* bt = btab + t * 6 + h;
    float rmax[4] = {-3.0e38f, -3.0e38f, -3.0e38f, -3.0e38f};
    #pragma unroll
    for (int ct = 0; ct < 9; ++ct) {
        int m = ct * 16 + l15;                 // C/D col = lane&15
        int zm = m / 72, rmm = m - zm * 72;
        int hm = rmm / 12, wmm = rmm - hm * 12;
        int mpart = 1656 * zm + 138 * hm - wmm;
        #pragma unroll
        for (int r = 0; r < 4; ++r) {
            float v = s[ct][r] * scale + bt[(size_t)(npart[r] + mpart) * 384]
                                       + mrow[nrow[r] * 144 + m];
            s[ct][r] = v;
            rmax[r] = fmaxf(rmax[r], v);
        }
    }
    #pragma unroll
    for (int off = 1; off < 16; off <<= 1) {
        #pragma unroll
        for (int r = 0; r < 4; ++r) rmax[r] = fmaxf(rmax[r], __shfl_xor(rmax[r], off));
    }
    float rsum[4] = {0.f, 0.f, 0.f, 0.f};
    #pragma unroll
    for (int ct = 0; ct < 9; ++ct) {
        #pragma unroll
        for (int r = 0; r < 4; ++r) {
            float e = __expf(s[ct][r] - rmax[r]);
            s[ct][r] = e;
            rsum[r] += e;
        }
    }
    #pragma unroll
    for (int off = 1; off < 16; off <<= 1) {
        #pragma unroll
        for (int r = 0; r < 4; ++r) rsum[r] += __shfl_xor(rsum[r], off);
    }
    float rinv[4];
    #pragma unroll
    for (int r = 0; r < 4; ++r) rinv[r] = 1.0f / rsum[r];

    #pragma unroll
    for (int ct = 0; ct < 9; ++ct) {
        #pragma unroll
        for (int r = 0; r < 4; ++r)
            pl[wv * 16 + g * 4 + r][ct * 16 + l15] = (bf16)(s[ct][r] * rinv[r]);
    }
    __asm__ __volatile__("s_waitcnt lgkmcnt(0)" ::: "memory");  // P writes -> P reads (same wave)

    // ---- P @ V  (5 K-steps of 32 over padded m=160) ----
    f32x4 o0 = (f32x4){0.f, 0.f, 0.f, 0.f};
    f32x4 o1 = (f32x4){0.f, 0.f, 0.f, 0.f};
    #pragma unroll
    for (int mc = 0; mc < 5; ++mc) {
        bf16x8 pa = *reinterpret_cast<const bf16x8*>(&pl[wv * 16 + l15][mc * 32 + g * 8]);
        bf16x8 v0 = *reinterpret_cast<const bf16x8*>(vp + (size_t)(0  + l15) * 144 + mc * 32 + g * 8);
        bf16x8 v1 = *reinterpret_cast<const bf16x8*>(vp + (size_t)(16 + l15) * 144 + mc * 32 + g * 8);
        o0 = MFMA16(pa, v0, o0);
        o1 = MFMA16(pa, v1, o1);
    }
    bf16* op = ob + (size_t)b * 27648 + h * 32;
    #pragma unroll
    for (int r = 0; r < 4; ++r) {
        int n = wv * 16 + g * 4 + r;
        op[(size_t)n * 192 + l15]      = (bf16)o0[r];
        op[(size_t)n * 192 + 16 + l15] = (bf16)o1[r];
    }
}

// ---------------- output projection GEMM ----------------
// grid 2160 (64 rows), 256 threads = 4 waves (row tiles)
__global__ __launch_bounds__(256) void k_out(const bf16* __restrict__ ob,
                                             const bf16* __restrict__ wt,
                                             const float* __restrict__ bout,
                                             float* __restrict__ out) {
    __shared__ bf16 wch[192][40];
    const int tid = threadIdx.x;
    const int lane = tid & 63;
    const int wid = tid >> 6;
    const int l15 = lane & 15;
    const int g = lane >> 4;
    const int m0 = blockIdx.x * 64;

    f32x4 acc[12];
    for (int i = 0; i < 12; ++i) acc[i] = (f32x4){0.f, 0.f, 0.f, 0.f};

    const bf16* orow = ob + (size_t)(m0 + wid * 16 + l15) * 192 + g * 8;

    for (int ks = 0; ks < 6; ++ks) {
        __syncthreads();
        for (int i = tid; i < 768; i += 256) {
            int row = i >> 2, c = i & 3;
            bf16x8 v = *reinterpret_cast<const bf16x8*>(wt + row * 192 + ks * 32 + c * 8);
            *reinterpret_cast<bf16x8*>(&wch[row][c * 8]) = v;
        }
        __syncthreads();
        bf16x8 a = *reinterpret_cast<const bf16x8*>(orow + ks * 32);
        #pragma unroll
        for (int ct = 0; ct < 12; ++ct) {
            bf16x8 b = *reinterpret_cast<const bf16x8*>(&wch[ct * 16 + l15][g * 8]);
            acc[ct] = MFMA16(a, b, acc[ct]);
        }
    }

    const int rowb = m0 + wid * 16 + g * 4;
    float* op = out + (size_t)rowb * 192;
    #pragma unroll
    for (int ct = 0; ct < 12; ++ct) {
        int c = ct * 16 + l15;
        float bias = bout[c];
        op[c]        = acc[ct][0] + bias;
        op[192 + c]  = acc[ct][1] + bias;
        op[384 + c]  = acc[ct][2] + bias;
        op[576 + c]  = acc[ct][3] + bias;
    }
}

extern "C" void kernel_launch(void* const* d_in, const int* in_sizes, int n_in,
                              void* d_out, int out_size, void* d_ws, size_t ws_size,
                              hipStream_t stream) {
    const float* x    = (const float*)d_in[0];
    const float* mask = (const float*)d_in[1];
    const float* wqkv = (const float*)d_in[2];
    const float* bqkv = (const float*)d_in[3];
    const float* wout = (const float*)d_in[4];
    const float* bout = (const float*)d_in[5];
    const float* btab = (const float*)d_in[6];
    float* out = (float*)d_out;

    char* ws = (char*)d_ws;
    bf16* wqkvt = (bf16*)(ws);
    bf16* woutt = (bf16*)(ws + 221184);
    bf16* qb    = (bf16*)(ws + 294912);
    bf16* kb    = (bf16*)(ws + 53379072);
    bf16* vtb   = (bf16*)(ws + 106463232);
    bf16* obuf  = (bf16*)(ws + 159547392);   // needs ~203 MiB of ws

    hipLaunchKernelGGL(k_prep, dim3(576),  dim3(256), 0, stream, wqkv, wout, wqkvt, woutt);
    hipLaunchKernelGGL(k_qkv,  dim3(2160), dim3(512), 0, stream, x, bqkv, wqkvt, qb, kb, vtb);
    hipLaunchKernelGGL(k_attn, dim3(5760), dim3(576), 0, stream, qb, kb, vtb, mask, btab, obuf);
    hipLaunchKernelGGL(k_out,  dim3(2160), dim3(256), 0, stream, obuf, woutt, bout, out);
}

// Round 2
// 353.481 us; speedup vs baseline: 1.4235x; 1.4235x over previous
//
#include <hip/hip_runtime.h>
#include <stdint.h>

typedef __bf16 bf16;
typedef __bf16 bf16x4 __attribute__((ext_vector_type(4)));
typedef __bf16 bf16x8 __attribute__((ext_vector_type(8)));
typedef float  f32x4  __attribute__((ext_vector_type(4)));

#define MFMA16(A, B, C) __builtin_amdgcn_mfma_f32_16x16x32_bf16((A), (B), (C), 0, 0, 0)

// Problem constants
// B=960 windows, N=144 patches, DIM=192, HEADS=6, hd=32, TYPES=64, n_mask=15
// ws layout (bytes):
//   wqkvt [576][192] bf16 @ 0           (221184)
//   woutt [192][192] bf16 @ 221184      (73728)   ends 294912
//   bias  [384][144][144] bf16 @ 294912 (15925248) ends 16220160
//   qb    [960][6][144][32] bf16 @ 16220160 (53084160) ends 69304320
//   kb    same @ 69304320  ends 122388480
//   vtb   [960][6][32][144] @ 122388480 ends 175472640
//   obuf  [960][144][192] @ 175472640   ends 228556800 (~218 MiB)

// ---------------- weight transpose + bf16 cast ----------------
__global__ __launch_bounds__(256) void k_prep(const float* __restrict__ wqkv,
                                              const float* __restrict__ wout,
                                              bf16* __restrict__ wqkvt,
                                              bf16* __restrict__ woutt) {
    int i = blockIdx.x * 256 + threadIdx.x;   // grid = 576 blocks -> i < 147456 exactly
    if (i < 576 * 192) {
        int n = i / 192, k = i - n * 192;
        wqkvt[i] = (bf16)wqkv[k * 576 + n];   // [n][k], k-contiguous
    } else {
        int j = i - 576 * 192;
        int n = j / 192, k = j - n * 192;
        woutt[j] = (bf16)wout[k * 192 + n];
    }
}

// ---------------- earth-bias materialization ----------------
// grid 384 = (t,h); each block stages its 3312-float table column in LDS,
// then writes the full gathered 144x144 slice coalesced as bf16.
__global__ __launch_bounds__(256) void k_bias(const float* __restrict__ btab,
                                              bf16* __restrict__ bias) {
    __shared__ float tb[3312];
    const int th = blockIdx.x;                 // t*6 + h
    for (int i = threadIdx.x; i < 3312; i += 256)
        tb[i] = btab[(size_t)i * 384 + th];
    __syncthreads();
    bf16* op = bias + (size_t)th * 20736;
    for (int o = threadIdx.x; o < 20736; o += 256) {
        int n = o / 144, m = o - n * 144;
        int zn = n / 72, rn = n - zn * 72, hn = rn / 12, wn = rn - hn * 12;
        int zm = m / 72, rm = m - zm * 72, hm = rm / 12, wm = rm - hm * 12;
        int idx = 828 * (zn + 2 * zm) + 23 * (hn + 6 * hm) + (wn - wm + 11);
        op[o] = (bf16)tb[idx];
    }
}

// ---------------- QKV projection GEMM ----------------
// grid 2160 (64 rows each), 512 threads = 8 waves: wave = (rt = wid&3 row-tile, ch = wid>>2 col-half)
__global__ __launch_bounds__(512) void k_qkv(const float* __restrict__ x,
                                             const float* __restrict__ bqkv,
                                             const bf16* __restrict__ wt,
                                             bf16* __restrict__ qb,
                                             bf16* __restrict__ kb,
                                             bf16* __restrict__ vtb) {
    __shared__ bf16 wch[576][40];   // k-step W chunk, padded 32->40 (2-way max bank conflict)
    const int tid = threadIdx.x;
    const int lane = tid & 63;
    const int wid = tid >> 6;
    const int rt = wid & 3;
    const int ch = wid >> 2;
    const int l15 = lane & 15;
    const int g = lane >> 4;
    const int m0 = blockIdx.x * 64;

    f32x4 acc[18];
    for (int i = 0; i < 18; ++i) acc[i] = (f32x4){0.f, 0.f, 0.f, 0.f};

    const float* xp = x + (size_t)(m0 + rt * 16 + l15) * 192 + g * 8;

    for (int ks = 0; ks < 6; ++ks) {
        __syncthreads();
        for (int i = tid; i < 2304; i += 512) {          // stage 576 rows x 32 k (36 KB)
            int row = i >> 2, c = i & 3;
            bf16x8 v = *reinterpret_cast<const bf16x8*>(wt + row * 192 + ks * 32 + c * 8);
            *reinterpret_cast<bf16x8*>(&wch[row][c * 8]) = v;
        }
        __syncthreads();
        f32x4 xa = *reinterpret_cast<const f32x4*>(xp + ks * 32);
        f32x4 xb = *reinterpret_cast<const f32x4*>(xp + ks * 32 + 4);
        bf16x8 a;
        a[0] = (bf16)xa[0]; a[1] = (bf16)xa[1]; a[2] = (bf16)xa[2]; a[3] = (bf16)xa[3];
        a[4] = (bf16)xb[0]; a[5] = (bf16)xb[1]; a[6] = (bf16)xb[2]; a[7] = (bf16)xb[3];
        #pragma unroll
        for (int ct = 0; ct < 18; ++ct) {
            int col = ch * 288 + ct * 16 + l15;
            bf16x8 b = *reinterpret_cast<const bf16x8*>(&wch[col][g * 8]);
            acc[ct] = MFMA16(a, b, acc[ct]);
        }
    }

    // epilogue: scatter to q (scaled, [b][h][n][32]), k ([b][h][n][32]), v transposed ([b][h][32][n])
    const float scale = 0.17677669529663687f;  // 1/sqrt(32), folded into q
    const int rowb = m0 + rt * 16 + g * 4;     // 4-row group, never crosses a 144 boundary
    const int bidx = rowb / 144;
    const int n0 = rowb - bidx * 144;
    #pragma unroll
    for (int ct = 0; ct < 18; ++ct) {
        int c = ch * 288 + ct * 16 + l15;      // global col in [0,576)
        float bias = bqkv[c];
        int qi = c / 192;
        int rem = c - qi * 192;
        int h = rem >> 5;
        int d = rem & 31;
        if (qi == 2) {
            bf16x4 v;
            v[0] = (bf16)(acc[ct][0] + bias);
            v[1] = (bf16)(acc[ct][1] + bias);
            v[2] = (bf16)(acc[ct][2] + bias);
            v[3] = (bf16)(acc[ct][3] + bias);
            *reinterpret_cast<bf16x4*>(vtb + ((size_t)(bidx * 6 + h) * 32 + d) * 144 + n0) = v;
        } else if (qi == 0) {
            bf16* dst = qb + ((size_t)(bidx * 6 + h) * 144 + n0) * 32 + d;
            dst[0]  = (bf16)((acc[ct][0] + bias) * scale);
            dst[32] = (bf16)((acc[ct][1] + bias) * scale);
            dst[64] = (bf16)((acc[ct][2] + bias) * scale);
            dst[96] = (bf16)((acc[ct][3] + bias) * scale);
        } else {
            bf16* dst = kb + ((size_t)(bidx * 6 + h) * 144 + n0) * 32 + d;
            dst[0]  = (bf16)(acc[ct][0] + bias);
            dst[32] = (bf16)(acc[ct][1] + bias);
            dst[64] = (bf16)(acc[ct][2] + bias);
            dst[96] = (bf16)(acc[ct][3] + bias);
        }
    }
}

// ---------------- windowed attention ----------------
// grid 5760 = (b,h); 576 threads = 9 waves; wave wv owns S rows [16wv,16wv+16)
__global__ __launch_bounds__(576) void k_attn(const bf16* __restrict__ qb,
                                              const bf16* __restrict__ kb,
                                              const bf16* __restrict__ vtb,
                                              const float* __restrict__ mask,
                                              const bf16* __restrict__ bias,
                                              bf16* __restrict__ ob) {
    __shared__ bf16 pl[144][168];   // P rows; m padded 144->160 zeros; stride 168 for banks
    const int bid = blockIdx.x;
    const int b = bid / 6;
    const int h = bid - b * 6;
    const int t = b & 63;           // bias type  = b % 64
    const int wm = b % 15;          // mask index = b % 15
    const int tid = threadIdx.x;
    const int lane = tid & 63;
    const int wv = tid >> 6;
    const int l15 = lane & 15;
    const int g = lane >> 4;

    const bf16* qp = qb + (size_t)bid * 4608;
    const bf16* kp = kb + (size_t)bid * 4608;
    const bf16* vp = vtb + (size_t)bid * 4608;

    // zero the m-pad columns [144,160) of this wave's own rows (no barrier needed)
    if (lane < 32) {
        bf16x8 z;
        #pragma unroll
        for (int i = 0; i < 8; ++i) z[i] = (bf16)0.f;
        *reinterpret_cast<bf16x8*>(&pl[wv * 16 + (lane >> 1)][144 + (lane & 1) * 8]) = z;
    }

    // ---- QK^T (hd=32 -> single K-step per 16x16 tile) ----
    bf16x8 aq = *reinterpret_cast<const bf16x8*>(qp + (wv * 16 + l15) * 32 + g * 8);
    f32x4 s[9];
    #pragma unroll
    for (int ct = 0; ct < 9; ++ct) {
        bf16x8 bk = *reinterpret_cast<const bf16x8*>(kp + (ct * 16 + l15) * 32 + g * 8);
        f32x4 z = (f32x4){0.f, 0.f, 0.f, 0.f};
        s[ct] = MFMA16(aq, bk, z);
    }

    // ---- + earth bias (precomputed, coalesced) + mask, fp32 softmax ----
    int nrow[4];
    #pragma unroll
    for (int r = 0; r < 4; ++r) nrow[r] = wv * 16 + g * 4 + r;  // C/D row = (lane>>4)*4 + reg
    const float* mrow = mask + (size_t)wm * 20736;
    const bf16* bp = bias + (size_t)(t * 6 + h) * 20736;
    float rmax[4] = {-3.0e38f, -3.0e38f, -3.0e38f, -3.0e38f};
    #pragma unroll
    for (int ct = 0; ct < 9; ++ct) {
        int m = ct * 16 + l15;                 // C/D col = lane&15
        #pragma unroll
        for (int r = 0; r < 4; ++r) {
            int off = nrow[r] * 144 + m;
            float v = s[ct][r] + (float)bp[off] + mrow[off];
            s[ct][r] = v;
            rmax[r] = fmaxf(rmax[r], v);
        }
    }
    #pragma unroll
    for (int off = 1; off < 16; off <<= 1) {
        #pragma unroll
        for (int r = 0; r < 4; ++r) rmax[r] = fmaxf(rmax[r], __shfl_xor(rmax[r], off));
    }
    float rsum[4] = {0.f, 0.f, 0.f, 0.f};
    #pragma unroll
    for (int ct = 0; ct < 9; ++ct) {
        #pragma unroll
        for (int r = 0; r < 4; ++r) {
            float e = __expf(s[ct][r] - rmax[r]);
            s[ct][r] = e;
            rsum[r] += e;
        }
    }
    #pragma unroll
    for (int off = 1; off < 16; off <<= 1) {
        #pragma unroll
        for (int r = 0; r < 4; ++r) rsum[r] += __shfl_xor(rsum[r], off);
    }
    float rinv[4];
    #pragma unroll
    for (int r = 0; r < 4; ++r) rinv[r] = 1.0f / rsum[r];

    #pragma unroll
    for (int ct = 0; ct < 9; ++ct) {
        #pragma unroll
        for (int r = 0; r < 4; ++r)
            pl[wv * 16 + g * 4 + r][ct * 16 + l15] = (bf16)(s[ct][r] * rinv[r]);
    }
    __asm__ __volatile__("s_waitcnt lgkmcnt(0)" ::: "memory");  // P writes -> P reads (same wave)

    // ---- P @ V  (5 K-steps of 32 over padded m=160) ----
    f32x4 o0 = (f32x4){0.f, 0.f, 0.f, 0.f};
    f32x4 o1 = (f32x4){0.f, 0.f, 0.f, 0.f};
    #pragma unroll
    for (int mc = 0; mc < 5; ++mc) {
        bf16x8 pa = *reinterpret_cast<const bf16x8*>(&pl[wv * 16 + l15][mc * 32 + g * 8]);
        bf16x8 v0 = *reinterpret_cast<const bf16x8*>(vp + (size_t)(0  + l15) * 144 + mc * 32 + g * 8);
        bf16x8 v1 = *reinterpret_cast<const bf16x8*>(vp + (size_t)(16 + l15) * 144 + mc * 32 + g * 8);
        o0 = MFMA16(pa, v0, o0);
        o1 = MFMA16(pa, v1, o1);
    }
    bf16* op = ob + (size_t)b * 27648 + h * 32;
    #pragma unroll
    for (int r = 0; r < 4; ++r) {
        int n = wv * 16 + g * 4 + r;
        op[(size_t)n * 192 + l15]      = (bf16)o0[r];
        op[(size_t)n * 192 + 16 + l15] = (bf16)o1[r];
    }
}

// ---------------- output projection GEMM ----------------
// grid 2160 (64 rows), 256 threads = 4 waves (row tiles)
__global__ __launch_bounds__(256) void k_out(const bf16* __restrict__ ob,
                                             const bf16* __restrict__ wt,
                                             const float* __restrict__ bout,
                                             float* __restrict__ out) {
    __shared__ bf16 wch[192][40];
    const int tid = threadIdx.x;
    const int lane = tid & 63;
    const int wid = tid >> 6;
    const int l15 = lane & 15;
    const int g = lane >> 4;
    const int m0 = blockIdx.x * 64;

    f32x4 acc[12];
    for (int i = 0; i < 12; ++i) acc[i] = (f32x4){0.f, 0.f, 0.f, 0.f};

    const bf16* orow = ob + (size_t)(m0 + wid * 16 + l15) * 192 + g * 8;

    for (int ks = 0; ks < 6; ++ks) {
        __syncthreads();
        for (int i = tid; i < 768; i += 256) {
            int row = i >> 2, c = i & 3;
            bf16x8 v = *reinterpret_cast<const bf16x8*>(wt + row * 192 + ks * 32 + c * 8);
            *reinterpret_cast<bf16x8*>(&wch[row][c * 8]) = v;
        }
        __syncthreads();
        bf16x8 a = *reinterpret_cast<const bf16x8*>(orow + ks * 32);
        #pragma unroll
        for (int ct = 0; ct < 12; ++ct) {
            bf16x8 b = *reinterpret_cast<const bf16x8*>(&wch[ct * 16 + l15][g * 8]);
            acc[ct] = MFMA16(a, b, acc[ct]);
        }
    }

    const int rowb = m0 + wid * 16 + g * 4;
    float* op = out + (size_t)rowb * 192;
    #pragma unroll
    for (int ct = 0; ct < 12; ++ct) {
        int c = ct * 16 + l15;
        float bias = bout[c];
        op[c]        = acc[ct][0] + bias;
        op[192 + c]  = acc[ct][1] + bias;
        op[384 + c]  = acc[ct][2] + bias;
        op[576 + c]  = acc[ct][3] + bias;
    }
}

extern "C" void kernel_launch(void* const* d_in, const int* in_sizes, int n_in,
                              void* d_out, int out_size, void* d_ws, size_t ws_size,
                              hipStream_t stream) {
    const float* x    = (const float*)d_in[0];
    const float* mask = (const float*)d_in[1];
    const float* wqkv = (const float*)d_in[2];
    const float* bqkv = (const float*)d_in[3];
    const float* wout = (const float*)d_in[4];
    const float* bout = (const float*)d_in[5];
    const float* btab = (const float*)d_in[6];
    float* out = (float*)d_out;

    char* ws = (char*)d_ws;
    bf16* wqkvt = (bf16*)(ws);
    bf16* woutt = (bf16*)(ws + 221184);
    bf16* bias  = (bf16*)(ws + 294912);
    bf16* qb    = (bf16*)(ws + 16220160);
    bf16* kb    = (bf16*)(ws + 69304320);
    bf16* vtb   = (bf16*)(ws + 122388480);
    bf16* obuf  = (bf16*)(ws + 175472640);   // needs ~218 MiB of ws

    hipLaunchKernelGGL(k_prep, dim3(576),  dim3(256), 0, stream, wqkv, wout, wqkvt, woutt);
    hipLaunchKernelGGL(k_bias, dim3(384),  dim3(256), 0, stream, btab, bias);
    hipLaunchKernelGGL(k_qkv,  dim3(2160), dim3(512), 0, stream, x, bqkv, wqkvt, qb, kb, vtb);
    hipLaunchKernelGGL(k_attn, dim3(5760), dim3(576), 0, stream, qb, kb, vtb, mask, bias, obuf);
    hipLaunchKernelGGL(k_out,  dim3(2160), dim3(256), 0, stream, obuf, woutt, bout, out);
}